// Round 1
// baseline (1029.682 us; speedup 1.0000x reference)
//
#include <hip/hip_runtime.h>
#include <math.h>

#define NN      8192
#define DIM     512      // IN_DIM == H*HID
#define NHEAD   8
#define HID     64
#define NE      262144
#define NE_HALF 131072
#define TOPK    10
#define NEGV    -9e15f
#define MAXDEG  512

// ---------------- GEMM: C[8192][512] = A[8192][512] @ B[512][512] (fp32) ----
#define BM 128
#define BN 64
#define BK 32

__global__ __launch_bounds__(256) void gemm_f(const float* __restrict__ A,
                                              const float* __restrict__ B,
                                              float* __restrict__ C) {
    __shared__ float As[BK][BM + 1];
    __shared__ float Bs[BK][BN + 1];
    const int bm = blockIdx.y * BM;
    const int bn = blockIdx.x * BN;
    const int tid = threadIdx.x;
    const int tx = tid & 15, ty = tid >> 4;
    float acc[8][4] = {};
    for (int kb = 0; kb < DIM; kb += BK) {
        // A tile 128x32: thread loads 4x float4 (transposed store)
        #pragma unroll
        for (int it = 0; it < 4; it++) {
            int r = (tid >> 3) + it * 32;
            int c = (tid & 7) * 4;
            float4 v = *(const float4*)(A + (size_t)(bm + r) * DIM + kb + c);
            As[c][r] = v.x; As[c + 1][r] = v.y; As[c + 2][r] = v.z; As[c + 3][r] = v.w;
        }
        // B tile 32x64: thread loads 2x float4
        #pragma unroll
        for (int it = 0; it < 2; it++) {
            int k = (tid >> 4) + it * 16;
            int n = (tid & 15) * 4;
            float4 v = *(const float4*)(B + (size_t)(kb + k) * DIM + bn + n);
            Bs[k][n] = v.x; Bs[k][n + 1] = v.y; Bs[k][n + 2] = v.z; Bs[k][n + 3] = v.w;
        }
        __syncthreads();
        #pragma unroll
        for (int k = 0; k < BK; k++) {
            float a[8], b[4];
            #pragma unroll
            for (int i = 0; i < 8; i++) a[i] = As[k][ty * 8 + i];
            #pragma unroll
            for (int j = 0; j < 4; j++) b[j] = Bs[k][tx * 4 + j];
            #pragma unroll
            for (int i = 0; i < 8; i++)
                #pragma unroll
                for (int j = 0; j < 4; j++) acc[i][j] += a[i] * b[j];
        }
        __syncthreads();
    }
    #pragma unroll
    for (int i = 0; i < 8; i++)
        #pragma unroll
        for (int j = 0; j < 4; j++)
            C[(size_t)(bm + ty * 8 + i) * DIM + bn + tx * 4 + j] = acc[i][j];
}

// ---------------- per-edge per-head dots + vals ----------------
// wave (64 lanes) per edge: lane l covers dims [l*8, l*8+8) -> head l>>3
__global__ __launch_bounds__(256) void edge_dots(const float* __restrict__ f,
                                                 const int* __restrict__ src,
                                                 const int* __restrict__ dst,
                                                 const float* __restrict__ trans,
                                                 float* __restrict__ e,
                                                 float* __restrict__ vals) {
    int j = blockIdx.x * 4 + (threadIdx.x >> 6);
    int lane = threadIdx.x & 63;
    const float4* ps = (const float4*)(f + (size_t)src[j] * DIM);
    const float4* pd = (const float4*)(f + (size_t)dst[j] * DIM);
    float4 a0 = ps[lane * 2], a1 = ps[lane * 2 + 1];
    float4 b0 = pd[lane * 2], b1 = pd[lane * 2 + 1];
    float p = a0.x * b0.x + a0.y * b0.y + a0.z * b0.z + a0.w * b0.w
            + a1.x * b1.x + a1.y * b1.y + a1.z * b1.z + a1.w * b1.w;
    p += __shfl_xor(p, 1);
    p += __shfl_xor(p, 2);
    p += __shfl_xor(p, 4);           // now: per-head sum at every lane of the 8-group
    if ((lane & 7) == 0) e[(size_t)j * NHEAD + (lane >> 3)] = p;
    p += __shfl_xor(p, 8);
    p += __shfl_xor(p, 16);
    p += __shfl_xor(p, 32);          // full 512-dim sum at all lanes
    if (lane == 0) vals[j] = trans[j] * p;
}

// ---------------- CSR by src ----------------
__global__ __launch_bounds__(256) void count_src(const int* __restrict__ src, int* counts) {
    int j = blockIdx.x * 256 + threadIdx.x;
    atomicAdd(&counts[src[j]], 1);
}

__global__ __launch_bounds__(256) void scan_offs(const int* __restrict__ counts,
                                                 int* __restrict__ offs, int* __restrict__ cur) {
    __shared__ int part[256];
    int t = threadIdx.x;
    int base = t * 32;
    int s = 0;
    for (int i = 0; i < 32; i++) s += counts[base + i];
    part[t] = s;
    __syncthreads();
    if (t == 0) {
        int run = 0;
        for (int i = 0; i < 256; i++) { int v = part[i]; part[i] = run; run += v; }
        offs[NN] = run;
    }
    __syncthreads();
    int run = part[t];
    for (int i = 0; i < 32; i++) {
        offs[base + i] = run;
        cur[base + i] = run;
        run += counts[base + i];
    }
}

__global__ __launch_bounds__(256) void scatter_src(const int* __restrict__ src,
                                                   int* cur, int* __restrict__ eid) {
    int j = blockIdx.x * 256 + threadIdx.x;
    int p = atomicAdd(&cur[src[j]], 1);
    eid[p] = j;
}

// ---------------- per-row coalesce + top-T threshold -> keep flags ----------
__global__ __launch_bounds__(128) void row_thresh(const int* __restrict__ offs,
                                                  const int* __restrict__ eid,
                                                  const int* __restrict__ dst,
                                                  const float* __restrict__ vals,
                                                  int* __restrict__ keep) {
    int r = blockIdx.x;
    int s0 = offs[r];
    int d = offs[r + 1] - s0;
    if (d > MAXDEG) d = MAXDEG;
    __shared__ int   sc[MAXDEG];
    __shared__ float sv[MAXDEG];
    __shared__ int   sj[MAXDEG];
    __shared__ float svc[MAXDEG];
    __shared__ unsigned char lead[MAXDEG];
    __shared__ float pos[MAXDEG];
    __shared__ float thr_s;
    for (int i = threadIdx.x; i < d; i += blockDim.x) {
        int j = eid[s0 + i];
        sj[i] = j; sc[i] = dst[j]; sv[i] = vals[j];
    }
    __syncthreads();
    for (int i = threadIdx.x; i < d; i += blockDim.x) {
        int c = sc[i];
        float sum = 0.f;
        bool leader = true;
        for (int k = 0; k < d; k++) {
            if (sc[k] == c) {
                sum += sv[k];
                if (k < i) leader = false;
            }
        }
        svc[i] = sum;
        lead[i] = leader ? 1 : 0;
    }
    __syncthreads();
    if (threadIdx.x == 0) {
        int p = 0;
        for (int i = 0; i < d; i++)
            if (lead[i] && svc[i] > 0.f) pos[p++] = svc[i];
        float thr = 0.f;
        if (p >= TOPK) {
            for (int t = 0; t < TOPK; t++) {
                int mi = 0; float mv = -1e30f;
                for (int i = 0; i < p; i++)
                    if (pos[i] > mv) { mv = pos[i]; mi = i; }
                thr = mv;
                pos[mi] = -1e30f;
            }
        }
        thr_s = thr;
    }
    __syncthreads();
    float thr = thr_s;
    for (int i = threadIdx.x; i < d; i += blockDim.x)
        keep[sj[i]] = (svc[i] >= thr) ? 1 : 0;
}

// ---------------- edge softmax by dst + aggregation + ELU ----------------
// block per dst node n. In-edges of n are rev(j) for j in src-CSR[n];
// in-edge rev(j): source = dst[j], e-row = e[rev(j)], mask = keep[j].
__global__ __launch_bounds__(256) void aggregate(const int* __restrict__ offs,
                                                 const int* __restrict__ eid,
                                                 const int* __restrict__ dst,
                                                 const float* __restrict__ e,
                                                 const int* __restrict__ keep,
                                                 const float* __restrict__ f,
                                                 float* __restrict__ z) {
    int n = blockIdx.x;
    int s0 = offs[n];
    int d = offs[n + 1] - s0;
    if (d > MAXDEG) d = MAXDEG;
    __shared__ float sa[MAXDEG][NHEAD];  // 16 KB
    __shared__ int ssrc[MAXDEG];
    __shared__ float sm[NHEAD], ss[NHEAD];
    for (int i = threadIdx.x; i < d; i += blockDim.x) {
        int j = eid[s0 + i];
        int rj = j ^ NE_HALF;
        ssrc[i] = dst[j];
        int kp = keep[j];
        const float* ep = e + (size_t)rj * NHEAD;
        #pragma unroll
        for (int h = 0; h < NHEAD; h++) sa[i][h] = kp ? ep[h] : NEGV;
    }
    __syncthreads();
    if (threadIdx.x < NHEAD) {
        int h = threadIdx.x;
        float m = -INFINITY;
        for (int i = 0; i < d; i++) m = fmaxf(m, sa[i][h]);
        float s = 0.f;
        for (int i = 0; i < d; i++) s += expf(sa[i][h] - m);
        sm[h] = m; ss[h] = s;
    }
    __syncthreads();
    for (int i = threadIdx.x; i < d * NHEAD; i += blockDim.x) {
        int ii = i >> 3, h = i & 7;
        sa[ii][h] = expf(sa[ii][h] - sm[h]) / ss[h];
    }
    __syncthreads();
    int c0 = threadIdx.x * 2;
    int h = c0 >> 6;
    float acc0 = 0.f, acc1 = 0.f;
    for (int i = 0; i < d; i++) {
        const float* row = f + (size_t)ssrc[i] * DIM;
        float a = sa[i][h];
        acc0 += a * row[c0];
        acc1 += a * row[c0 + 1];
    }
    acc0 = acc0 > 0.f ? acc0 : expf(acc0) - 1.f;   // elu
    acc1 = acc1 > 0.f ? acc1 : expf(acc1) - 1.f;
    z[(size_t)n * DIM + c0] = acc0;
    z[(size_t)n * DIM + c0 + 1] = acc1;
}

// ---------------- semantic attention scores ----------------
__global__ __launch_bounds__(128) void sem_scores(const float* __restrict__ z0,
                                                  const float* __restrict__ z1,
                                                  const float* __restrict__ w1,
                                                  const float* __restrict__ b1,
                                                  const float* __restrict__ w2,
                                                  float* wsum) {
    int n = blockIdx.x;
    __shared__ float zrow[DIM];
    __shared__ float red[128];
    int k = threadIdx.x;
    for (int m = 0; m < 2; m++) {
        const float* z = m ? z1 : z0;
        for (int i = k; i < DIM; i += 128) zrow[i] = z[(size_t)n * DIM + i];
        __syncthreads();
        float acc = b1[k];
        for (int dd = 0; dd < DIM; dd++) acc += zrow[dd] * w1[dd * 128 + k];
        red[k] = tanhf(acc) * w2[k];
        __syncthreads();
        for (int s = 64; s > 0; s >>= 1) {
            if (k < s) red[k] += red[k + s];
            __syncthreads();
        }
        if (k == 0) atomicAdd(&wsum[m], red[0]);
        __syncthreads();
    }
}

// ---------------- final: beta-weighted combine + linear ----------------
__global__ __launch_bounds__(256) void final_out(const float* __restrict__ z0,
                                                 const float* __restrict__ z1,
                                                 const float* __restrict__ wsum,
                                                 const float* __restrict__ lin_w,
                                                 const float* __restrict__ lin_b,
                                                 float* __restrict__ out) {
    int idx = blockIdx.x * 256 + threadIdx.x;   // 24576 threads
    int n = idx / 3, o = idx - n * 3;
    float w0 = wsum[0] * (1.0f / NN), w1v = wsum[1] * (1.0f / NN);
    float mx = fmaxf(w0, w1v);
    float e0 = expf(w0 - mx), e1 = expf(w1v - mx);
    float beta0 = e0 / (e0 + e1), beta1 = e1 / (e0 + e1);
    const float* p0 = z0 + (size_t)n * DIM;
    const float* p1 = z1 + (size_t)n * DIM;
    float acc = 0.f;
    for (int dd = 0; dd < DIM; dd++)
        acc += (beta0 * p0[dd] + beta1 * p1[dd]) * lin_w[dd * 3 + o];
    out[idx] = acc + lin_b[o];
}

// ---------------- launch ----------------
extern "C" void kernel_launch(void* const* d_in, const int* in_sizes, int n_in,
                              void* d_out, int out_size, void* d_ws, size_t ws_size,
                              hipStream_t stream) {
    const float* feat = (const float*)d_in[0];
    const int*   srcp[2]   = { (const int*)d_in[1], (const int*)d_in[4] };
    const int*   dstp[2]   = { (const int*)d_in[2], (const int*)d_in[5] };
    const float* transp[2] = { (const float*)d_in[3], (const float*)d_in[6] };
    const float* fcw[2]    = { (const float*)d_in[7], (const float*)d_in[8] };
    const float* sem_w1 = (const float*)d_in[9];
    const float* sem_b1 = (const float*)d_in[10];
    const float* sem_w2 = (const float*)d_in[11];
    const float* lin_w  = (const float*)d_in[12];
    const float* lin_b  = (const float*)d_in[13];
    float* out = (float*)d_out;

    char* ws = (char*)d_ws;
    const size_t MB = 1 << 20;
    if (ws_size < 61 * MB) return;   // need ~60 MB scratch
    float* f     = (float*)(ws);
    float* z0    = (float*)(ws + 16 * MB);
    float* z1    = (float*)(ws + 32 * MB);
    float* e     = (float*)(ws + 48 * MB);
    float* vals  = (float*)(ws + 56 * MB);
    int*   keep  = (int*)  (ws + 57 * MB);
    int*   eid   = (int*)  (ws + 58 * MB);
    int*   counts= (int*)  (ws + 59 * MB);
    int*   offs  = (int*)  (ws + 59 * MB + 65536);
    int*   cur   = (int*)  (ws + 59 * MB + 131072);
    float* wsum  = (float*)(ws + 59 * MB + 196608);

    for (int c = 0; c < 2; c++) {
        float* z = c ? z1 : z0;
        gemm_f<<<dim3(DIM / BN, NN / BM), 256, 0, stream>>>(feat, fcw[c], f);
        edge_dots<<<NE / 4, 256, 0, stream>>>(f, srcp[c], dstp[c], transp[c], e, vals);
        hipMemsetAsync(counts, 0, NN * sizeof(int), stream);
        count_src<<<NE / 256, 256, 0, stream>>>(srcp[c], counts);
        scan_offs<<<1, 256, 0, stream>>>(counts, offs, cur);
        scatter_src<<<NE / 256, 256, 0, stream>>>(srcp[c], cur, eid);
        row_thresh<<<NN, 128, 0, stream>>>(offs, eid, dstp[c], vals, keep);
        aggregate<<<NN, 256, 0, stream>>>(offs, eid, dstp[c], e, keep, f, z);
    }
    hipMemsetAsync(wsum, 0, 2 * sizeof(float), stream);
    sem_scores<<<NN, 128, 0, stream>>>(z0, z1, sem_w1, sem_b1, sem_w2, wsum);
    final_out<<<(NN * 3) / 256, 256, 0, stream>>>(z0, z1, wsum, lin_w, lin_b, out);
}

// Round 2
// 873.379 us; speedup vs baseline: 1.1790x; 1.1790x over previous
//
#include <hip/hip_runtime.h>
#include <math.h>

#define NN      8192
#define DIM     512      // IN_DIM == H*HID
#define NHEAD   8
#define HID     64
#define NE      262144
#define NE_HALF 131072
#define TOPK    10
#define NEGV    -9e15f
#define MAXDEG  512

// ---------------- GEMM: C[8192][512] = A[8192][512] @ B[512][512] (fp32) ----
#define BM 128
#define BN 64
#define BK 32

__global__ __launch_bounds__(256) void gemm_f(const float* __restrict__ A,
                                              const float* __restrict__ B,
                                              float* __restrict__ C) {
    __shared__ float As[BK][BM + 1];
    __shared__ float Bs[BK][BN + 1];
    const int bm = blockIdx.y * BM;
    const int bn = blockIdx.x * BN;
    const int tid = threadIdx.x;
    const int tx = tid & 15, ty = tid >> 4;
    float acc[8][4] = {};
    for (int kb = 0; kb < DIM; kb += BK) {
        // A tile 128x32: thread loads 4x float4 (transposed store)
        #pragma unroll
        for (int it = 0; it < 4; it++) {
            int r = (tid >> 3) + it * 32;
            int c = (tid & 7) * 4;
            float4 v = *(const float4*)(A + (size_t)(bm + r) * DIM + kb + c);
            As[c][r] = v.x; As[c + 1][r] = v.y; As[c + 2][r] = v.z; As[c + 3][r] = v.w;
        }
        // B tile 32x64: thread loads 2x float4
        #pragma unroll
        for (int it = 0; it < 2; it++) {
            int k = (tid >> 4) + it * 16;
            int n = (tid & 15) * 4;
            float4 v = *(const float4*)(B + (size_t)(kb + k) * DIM + bn + n);
            Bs[k][n] = v.x; Bs[k][n + 1] = v.y; Bs[k][n + 2] = v.z; Bs[k][n + 3] = v.w;
        }
        __syncthreads();
        #pragma unroll
        for (int k = 0; k < BK; k++) {
            float a[8], b[4];
            #pragma unroll
            for (int i = 0; i < 8; i++) a[i] = As[k][ty * 8 + i];
            #pragma unroll
            for (int j = 0; j < 4; j++) b[j] = Bs[k][tx * 4 + j];
            #pragma unroll
            for (int i = 0; i < 8; i++)
                #pragma unroll
                for (int j = 0; j < 4; j++) acc[i][j] += a[i] * b[j];
        }
        __syncthreads();
    }
    #pragma unroll
    for (int i = 0; i < 8; i++)
        #pragma unroll
        for (int j = 0; j < 4; j++)
            C[(size_t)(bm + ty * 8 + i) * DIM + bn + tx * 4 + j] = acc[i][j];
}

// ---------------- per-edge per-head dots + vals ----------------
// wave (64 lanes) per edge: lane l covers dims [l*8, l*8+8) -> head l>>3
__global__ __launch_bounds__(256) void edge_dots(const float* __restrict__ f,
                                                 const int* __restrict__ src,
                                                 const int* __restrict__ dst,
                                                 const float* __restrict__ trans,
                                                 float* __restrict__ e,
                                                 float* __restrict__ vals) {
    int j = blockIdx.x * 4 + (threadIdx.x >> 6);
    int lane = threadIdx.x & 63;
    const float4* ps = (const float4*)(f + (size_t)src[j] * DIM);
    const float4* pd = (const float4*)(f + (size_t)dst[j] * DIM);
    float4 a0 = ps[lane * 2], a1 = ps[lane * 2 + 1];
    float4 b0 = pd[lane * 2], b1 = pd[lane * 2 + 1];
    float p = a0.x * b0.x + a0.y * b0.y + a0.z * b0.z + a0.w * b0.w
            + a1.x * b1.x + a1.y * b1.y + a1.z * b1.z + a1.w * b1.w;
    p += __shfl_xor(p, 1);
    p += __shfl_xor(p, 2);
    p += __shfl_xor(p, 4);           // now: per-head sum at every lane of the 8-group
    if ((lane & 7) == 0) e[(size_t)j * NHEAD + (lane >> 3)] = p;
    p += __shfl_xor(p, 8);
    p += __shfl_xor(p, 16);
    p += __shfl_xor(p, 32);          // full 512-dim sum at all lanes
    if (lane == 0) vals[j] = trans[j] * p;
}

// ---------------- CSR by src ----------------
__global__ __launch_bounds__(256) void count_src(const int* __restrict__ src, int* counts) {
    int j = blockIdx.x * 256 + threadIdx.x;
    atomicAdd(&counts[src[j]], 1);
}

__global__ __launch_bounds__(256) void scan_offs(const int* __restrict__ counts,
                                                 int* __restrict__ offs, int* __restrict__ cur) {
    __shared__ int part[256];
    int t = threadIdx.x;
    int base = t * 32;
    int s = 0;
    for (int i = 0; i < 32; i++) s += counts[base + i];
    part[t] = s;
    __syncthreads();
    if (t == 0) {
        int run = 0;
        for (int i = 0; i < 256; i++) { int v = part[i]; part[i] = run; run += v; }
        offs[NN] = run;
    }
    __syncthreads();
    int run = part[t];
    for (int i = 0; i < 32; i++) {
        offs[base + i] = run;
        cur[base + i] = run;
        run += counts[base + i];
    }
}

__global__ __launch_bounds__(256) void scatter_src(const int* __restrict__ src,
                                                   int* cur, int* __restrict__ eid) {
    int j = blockIdx.x * 256 + threadIdx.x;
    int p = atomicAdd(&cur[src[j]], 1);
    eid[p] = j;
}

// ---------------- per-row coalesce + top-T threshold -> keep flags ----------
__global__ __launch_bounds__(128) void row_thresh(const int* __restrict__ offs,
                                                  const int* __restrict__ eid,
                                                  const int* __restrict__ dst,
                                                  const float* __restrict__ vals,
                                                  int* __restrict__ keep) {
    int r = blockIdx.x;
    int s0 = offs[r];
    int d = offs[r + 1] - s0;
    if (d > MAXDEG) d = MAXDEG;
    __shared__ int   sc[MAXDEG];
    __shared__ float sv[MAXDEG];
    __shared__ int   sj[MAXDEG];
    __shared__ float svc[MAXDEG];
    __shared__ unsigned char lead[MAXDEG];
    __shared__ float pos[MAXDEG];
    __shared__ float thr_s;
    for (int i = threadIdx.x; i < d; i += blockDim.x) {
        int j = eid[s0 + i];
        sj[i] = j; sc[i] = dst[j]; sv[i] = vals[j];
    }
    __syncthreads();
    for (int i = threadIdx.x; i < d; i += blockDim.x) {
        int c = sc[i];
        float sum = 0.f;
        bool leader = true;
        for (int k = 0; k < d; k++) {
            if (sc[k] == c) {
                sum += sv[k];
                if (k < i) leader = false;
            }
        }
        svc[i] = sum;
        lead[i] = leader ? 1 : 0;
    }
    __syncthreads();
    if (threadIdx.x == 0) {
        int p = 0;
        for (int i = 0; i < d; i++)
            if (lead[i] && svc[i] > 0.f) pos[p++] = svc[i];
        float thr = 0.f;
        if (p >= TOPK) {
            for (int t = 0; t < TOPK; t++) {
                int mi = 0; float mv = -1e30f;
                for (int i = 0; i < p; i++)
                    if (pos[i] > mv) { mv = pos[i]; mi = i; }
                thr = mv;
                pos[mi] = -1e30f;
            }
        }
        thr_s = thr;
    }
    __syncthreads();
    float thr = thr_s;
    for (int i = threadIdx.x; i < d; i += blockDim.x)
        keep[sj[i]] = (svc[i] >= thr) ? 1 : 0;
}

// ---------------- edge softmax by dst + aggregation + ELU ----------------
// block per dst node n. In-edges of n are rev(j) for j in src-CSR[n];
// in-edge rev(j): source = dst[j], e-row = e[rev(j)], mask = keep[j].
__global__ __launch_bounds__(256) void aggregate(const int* __restrict__ offs,
                                                 const int* __restrict__ eid,
                                                 const int* __restrict__ dst,
                                                 const float* __restrict__ e,
                                                 const int* __restrict__ keep,
                                                 const float* __restrict__ f,
                                                 float* __restrict__ z) {
    int n = blockIdx.x;
    int s0 = offs[n];
    int d = offs[n + 1] - s0;
    if (d > MAXDEG) d = MAXDEG;
    __shared__ float sa[MAXDEG][NHEAD];  // 16 KB
    __shared__ int ssrc[MAXDEG];
    __shared__ float sm[NHEAD], ss[NHEAD];
    for (int i = threadIdx.x; i < d; i += blockDim.x) {
        int j = eid[s0 + i];
        int rj = j ^ NE_HALF;
        ssrc[i] = dst[j];
        int kp = keep[j];
        const float* ep = e + (size_t)rj * NHEAD;
        #pragma unroll
        for (int h = 0; h < NHEAD; h++) sa[i][h] = kp ? ep[h] : NEGV;
    }
    __syncthreads();
    if (threadIdx.x < NHEAD) {
        int h = threadIdx.x;
        float m = -INFINITY;
        for (int i = 0; i < d; i++) m = fmaxf(m, sa[i][h]);
        float s = 0.f;
        for (int i = 0; i < d; i++) s += expf(sa[i][h] - m);
        sm[h] = m; ss[h] = s;
    }
    __syncthreads();
    for (int i = threadIdx.x; i < d * NHEAD; i += blockDim.x) {
        int ii = i >> 3, h = i & 7;
        sa[ii][h] = expf(sa[ii][h] - sm[h]) / ss[h];
    }
    __syncthreads();
    int c0 = threadIdx.x * 2;
    int h = c0 >> 6;
    float acc0 = 0.f, acc1 = 0.f;
    for (int i = 0; i < d; i++) {
        const float* row = f + (size_t)ssrc[i] * DIM;
        float a = sa[i][h];
        acc0 += a * row[c0];
        acc1 += a * row[c0 + 1];
    }
    acc0 = acc0 > 0.f ? acc0 : expf(acc0) - 1.f;   // elu
    acc1 = acc1 > 0.f ? acc1 : expf(acc1) - 1.f;
    z[(size_t)n * DIM + c0] = acc0;
    z[(size_t)n * DIM + c0 + 1] = acc1;
}

// ---------------- semantic attention scores (tiled GEMM + fused tanh) -------
// wsum[m] += sum over nodes of tanh(z_m @ w1 + b1) @ w2
// grid: (NN/SBM, 2); block 256 = 16x16; each thread 4 rows x 8 cols.
#define SBM 64
#define SBN 128
#define SBK 32

__global__ __launch_bounds__(256) void sem_scores2(const float* __restrict__ z0,
                                                   const float* __restrict__ z1,
                                                   const float* __restrict__ w1,
                                                   const float* __restrict__ b1,
                                                   const float* __restrict__ w2,
                                                   float* wsum) {
    const float* Z = blockIdx.y ? z1 : z0;
    const int bm = blockIdx.x * SBM;
    const int tid = threadIdx.x;
    const int tx = tid & 15, ty = tid >> 4;
    __shared__ float Zs[SBK][SBM + 1];
    __shared__ float Ws[SBK][SBN + 1];
    float acc[4][8] = {};
    for (int kb = 0; kb < DIM; kb += SBK) {
        // Z tile 64 rows x 32 k (transposed store)
        #pragma unroll
        for (int it = 0; it < 2; it++) {
            int r = (tid >> 3) + it * 32;
            int c = (tid & 7) * 4;
            float4 v = *(const float4*)(Z + (size_t)(bm + r) * DIM + kb + c);
            Zs[c][r] = v.x; Zs[c + 1][r] = v.y; Zs[c + 2][r] = v.z; Zs[c + 3][r] = v.w;
        }
        // W1 tile 32 k x 128 cols (row-major stride 128)
        #pragma unroll
        for (int it = 0; it < 4; it++) {
            int k = (tid >> 5) + it * 8;
            int n = (tid & 31) * 4;
            float4 v = *(const float4*)(w1 + (size_t)(kb + k) * SBN + n);
            Ws[k][n] = v.x; Ws[k][n + 1] = v.y; Ws[k][n + 2] = v.z; Ws[k][n + 3] = v.w;
        }
        __syncthreads();
        #pragma unroll
        for (int k = 0; k < SBK; k++) {
            float a[4], b[8];
            #pragma unroll
            for (int i = 0; i < 4; i++) a[i] = Zs[k][ty * 4 + i];
            #pragma unroll
            for (int j = 0; j < 8; j++) b[j] = Ws[k][tx * 8 + j];
            #pragma unroll
            for (int i = 0; i < 4; i++)
                #pragma unroll
                for (int j = 0; j < 8; j++) acc[i][j] += a[i] * b[j];
        }
        __syncthreads();
    }
    // fused epilogue: tanh -> *w2 -> total sum (only mean over nodes is needed)
    float local = 0.f;
    #pragma unroll
    for (int j = 0; j < 8; j++) {
        int col = tx * 8 + j;
        float bb = b1[col], ww = w2[col];
        #pragma unroll
        for (int i = 0; i < 4; i++)
            local += tanhf(acc[i][j] + bb) * ww;
    }
    __shared__ float red[256];
    red[tid] = local;
    __syncthreads();
    for (int s = 128; s > 0; s >>= 1) {
        if (tid < s) red[tid] += red[tid + s];
        __syncthreads();
    }
    if (tid == 0) atomicAdd(&wsum[blockIdx.y], red[0]);
}

// ---------------- final: beta-weighted combine + linear ----------------
__global__ __launch_bounds__(256) void final_out(const float* __restrict__ z0,
                                                 const float* __restrict__ z1,
                                                 const float* __restrict__ wsum,
                                                 const float* __restrict__ lin_w,
                                                 const float* __restrict__ lin_b,
                                                 float* __restrict__ out) {
    int idx = blockIdx.x * 256 + threadIdx.x;   // 24576 threads
    int n = idx / 3, o = idx - n * 3;
    float w0 = wsum[0] * (1.0f / NN), w1v = wsum[1] * (1.0f / NN);
    float mx = fmaxf(w0, w1v);
    float e0 = expf(w0 - mx), e1 = expf(w1v - mx);
    float beta0 = e0 / (e0 + e1), beta1 = e1 / (e0 + e1);
    const float* p0 = z0 + (size_t)n * DIM;
    const float* p1 = z1 + (size_t)n * DIM;
    float acc = 0.f;
    for (int dd = 0; dd < DIM; dd++)
        acc += (beta0 * p0[dd] + beta1 * p1[dd]) * lin_w[dd * 3 + o];
    out[idx] = acc + lin_b[o];
}

// ---------------- launch ----------------
extern "C" void kernel_launch(void* const* d_in, const int* in_sizes, int n_in,
                              void* d_out, int out_size, void* d_ws, size_t ws_size,
                              hipStream_t stream) {
    const float* feat = (const float*)d_in[0];
    const int*   srcp[2]   = { (const int*)d_in[1], (const int*)d_in[4] };
    const int*   dstp[2]   = { (const int*)d_in[2], (const int*)d_in[5] };
    const float* transp[2] = { (const float*)d_in[3], (const float*)d_in[6] };
    const float* fcw[2]    = { (const float*)d_in[7], (const float*)d_in[8] };
    const float* sem_w1 = (const float*)d_in[9];
    const float* sem_b1 = (const float*)d_in[10];
    const float* sem_w2 = (const float*)d_in[11];
    const float* lin_w  = (const float*)d_in[12];
    const float* lin_b  = (const float*)d_in[13];
    float* out = (float*)d_out;

    char* ws = (char*)d_ws;
    const size_t MB = 1 << 20;
    if (ws_size < 61 * MB) return;   // need ~60 MB scratch
    float* f     = (float*)(ws);
    float* z0    = (float*)(ws + 16 * MB);
    float* z1    = (float*)(ws + 32 * MB);
    float* e     = (float*)(ws + 48 * MB);
    float* vals  = (float*)(ws + 56 * MB);
    int*   keep  = (int*)  (ws + 57 * MB);
    int*   eid   = (int*)  (ws + 58 * MB);
    int*   counts= (int*)  (ws + 59 * MB);
    int*   offs  = (int*)  (ws + 59 * MB + 65536);
    int*   cur   = (int*)  (ws + 59 * MB + 131072);
    float* wsum  = (float*)(ws + 59 * MB + 196608);

    for (int c = 0; c < 2; c++) {
        float* z = c ? z1 : z0;
        gemm_f<<<dim3(DIM / BN, NN / BM), 256, 0, stream>>>(feat, fcw[c], f);
        edge_dots<<<NE / 4, 256, 0, stream>>>(f, srcp[c], dstp[c], transp[c], e, vals);
        hipMemsetAsync(counts, 0, NN * sizeof(int), stream);
        count_src<<<NE / 256, 256, 0, stream>>>(srcp[c], counts);
        scan_offs<<<1, 256, 0, stream>>>(counts, offs, cur);
        scatter_src<<<NE / 256, 256, 0, stream>>>(srcp[c], cur, eid);
        row_thresh<<<NN, 128, 0, stream>>>(offs, eid, dstp[c], vals, keep);
        aggregate<<<NN, 256, 0, stream>>>(offs, eid, dstp[c], e, keep, f, z);
    }
    hipMemsetAsync(wsum, 0, 2 * sizeof(float), stream);
    sem_scores2<<<dim3(NN / SBM, 2), 256, 0, stream>>>(z0, z1, sem_w1, sem_b1, sem_w2, wsum);
    final_out<<<(NN * 3) / 256, 256, 0, stream>>>(z0, z1, wsum, lin_w, lin_b, out);
}

// Round 3
// 754.451 us; speedup vs baseline: 1.3648x; 1.1576x over previous
//
#include <hip/hip_runtime.h>
#include <math.h>

#define NN      8192
#define DIM     512      // IN_DIM == H*HID
#define NHEAD   8
#define HID     64
#define NE      262144
#define NE_HALF 131072
#define TOPK    10
#define NEGV    -9e15f
#define MAXDEG  512

__device__ __forceinline__ float bf2f(unsigned int h) {
    return __uint_as_float(h << 16);
}
__device__ __forceinline__ unsigned short f2bf(float x) {
    unsigned int u = __float_as_uint(x);
    unsigned int r = (u + 0x7fff + ((u >> 16) & 1)) >> 16;   // RNE
    return (unsigned short)r;
}

// ---------------- GEMM: C[8192][512] = A[8192][512] @ B[512][512] (fp32) ----
// also writes a bf16 mirror of C for the aggregation pass
#define BM 128
#define BN 64
#define BK 32

__global__ __launch_bounds__(256) void gemm_f(const float* __restrict__ A,
                                              const float* __restrict__ B,
                                              float* __restrict__ C,
                                              unsigned short* __restrict__ Cb) {
    __shared__ float As[BK][BM + 1];
    __shared__ float Bs[BK][BN + 1];
    const int bm = blockIdx.y * BM;
    const int bn = blockIdx.x * BN;
    const int tid = threadIdx.x;
    const int tx = tid & 15, ty = tid >> 4;
    float acc[8][4] = {};
    for (int kb = 0; kb < DIM; kb += BK) {
        #pragma unroll
        for (int it = 0; it < 4; it++) {
            int r = (tid >> 3) + it * 32;
            int c = (tid & 7) * 4;
            float4 v = *(const float4*)(A + (size_t)(bm + r) * DIM + kb + c);
            As[c][r] = v.x; As[c + 1][r] = v.y; As[c + 2][r] = v.z; As[c + 3][r] = v.w;
        }
        #pragma unroll
        for (int it = 0; it < 2; it++) {
            int k = (tid >> 4) + it * 16;
            int n = (tid & 15) * 4;
            float4 v = *(const float4*)(B + (size_t)(kb + k) * DIM + bn + n);
            Bs[k][n] = v.x; Bs[k][n + 1] = v.y; Bs[k][n + 2] = v.z; Bs[k][n + 3] = v.w;
        }
        __syncthreads();
        #pragma unroll
        for (int k = 0; k < BK; k++) {
            float a[8], b[4];
            #pragma unroll
            for (int i = 0; i < 8; i++) a[i] = As[k][ty * 8 + i];
            #pragma unroll
            for (int j = 0; j < 4; j++) b[j] = Bs[k][tx * 4 + j];
            #pragma unroll
            for (int i = 0; i < 8; i++)
                #pragma unroll
                for (int j = 0; j < 4; j++) acc[i][j] += a[i] * b[j];
        }
        __syncthreads();
    }
    #pragma unroll
    for (int i = 0; i < 8; i++)
        #pragma unroll
        for (int j = 0; j < 4; j++) {
            size_t off = (size_t)(bm + ty * 8 + i) * DIM + bn + tx * 4 + j;
            C[off] = acc[i][j];
            Cb[off] = f2bf(acc[i][j]);
        }
}

// ---------------- CSR by src ----------------
__global__ __launch_bounds__(256) void count_src(const int* __restrict__ src, int* counts) {
    int j = blockIdx.x * 256 + threadIdx.x;
    atomicAdd(&counts[src[j]], 1);
}

__global__ __launch_bounds__(256) void scan_offs(const int* __restrict__ counts,
                                                 int* __restrict__ offs, int* __restrict__ cur) {
    __shared__ int part[256];
    int t = threadIdx.x;
    int base = t * 32;
    int s = 0;
    for (int i = 0; i < 32; i++) s += counts[base + i];
    part[t] = s;
    __syncthreads();
    if (t == 0) {
        int run = 0;
        for (int i = 0; i < 256; i++) { int v = part[i]; part[i] = run; run += v; }
        offs[NN] = run;
    }
    __syncthreads();
    int run = part[t];
    for (int i = 0; i < 32; i++) {
        offs[base + i] = run;
        cur[base + i] = run;
        run += counts[base + i];
    }
}

__global__ __launch_bounds__(256) void scatter_src(const int* __restrict__ src,
                                                   int* cur, int* __restrict__ eid) {
    int j = blockIdx.x * 256 + threadIdx.x;
    int p = atomicAdd(&cur[src[j]], 1);
    eid[p] = j;
}

// ---------------- per-edge per-head dots + vals (CSR order) ----------------
// block per src node n; src row read once (registers), dst rows streamed.
// e[j][h] = head-h dot of f[src[j]],f[dst[j]]  (symmetric: e[rev(j)]==e[j])
__global__ __launch_bounds__(256) void edge_dots_csr(const float* __restrict__ f,
                                                     const int* __restrict__ offs,
                                                     const int* __restrict__ eid,
                                                     const int* __restrict__ dst,
                                                     const float* __restrict__ trans,
                                                     float* __restrict__ e,
                                                     float* __restrict__ vals) {
    int n = blockIdx.x;
    int s0 = offs[n];
    int d = offs[n + 1] - s0;
    if (d <= 0) return;
    int wave = threadIdx.x >> 6, lane = threadIdx.x & 63;
    const float4* ps = (const float4*)(f + (size_t)n * DIM);
    float4 a0 = ps[lane * 2], a1 = ps[lane * 2 + 1];
    for (int i = wave; i < d; i += 4) {
        int j = eid[s0 + i];
        const float4* pd = (const float4*)(f + (size_t)dst[j] * DIM);
        float4 b0 = pd[lane * 2], b1 = pd[lane * 2 + 1];
        float p = a0.x * b0.x + a0.y * b0.y + a0.z * b0.z + a0.w * b0.w
                + a1.x * b1.x + a1.y * b1.y + a1.z * b1.z + a1.w * b1.w;
        p += __shfl_xor(p, 1);
        p += __shfl_xor(p, 2);
        p += __shfl_xor(p, 4);           // per-head sums (head = lane>>3)
        if ((lane & 7) == 0) e[(size_t)j * NHEAD + (lane >> 3)] = p;
        p += __shfl_xor(p, 8);
        p += __shfl_xor(p, 16);
        p += __shfl_xor(p, 32);          // full 512-dim sum
        if (lane == 0) vals[j] = trans[j] * p;
    }
}

// ---------------- per-row coalesce + top-T threshold -> keep flags ----------
__global__ __launch_bounds__(128) void row_thresh(const int* __restrict__ offs,
                                                  const int* __restrict__ eid,
                                                  const int* __restrict__ dst,
                                                  const float* __restrict__ vals,
                                                  unsigned char* __restrict__ keep) {
    int r = blockIdx.x;
    int s0 = offs[r];
    int d = offs[r + 1] - s0;
    if (d > MAXDEG) d = MAXDEG;
    __shared__ int   sc[MAXDEG];
    __shared__ float sv[MAXDEG];
    __shared__ int   sj[MAXDEG];
    __shared__ float svc[MAXDEG];
    __shared__ unsigned char lead[MAXDEG];
    __shared__ float pos[MAXDEG];
    __shared__ float thr_s;
    for (int i = threadIdx.x; i < d; i += blockDim.x) {
        int j = eid[s0 + i];
        sj[i] = j; sc[i] = dst[j]; sv[i] = vals[j];
    }
    __syncthreads();
    for (int i = threadIdx.x; i < d; i += blockDim.x) {
        int c = sc[i];
        float sum = 0.f;
        bool leader = true;
        for (int k = 0; k < d; k++) {
            if (sc[k] == c) {
                sum += sv[k];
                if (k < i) leader = false;
            }
        }
        svc[i] = sum;
        lead[i] = leader ? 1 : 0;
    }
    __syncthreads();
    if (threadIdx.x == 0) {
        int p = 0;
        for (int i = 0; i < d; i++)
            if (lead[i] && svc[i] > 0.f) pos[p++] = svc[i];
        float thr = 0.f;
        if (p >= TOPK) {
            for (int t = 0; t < TOPK; t++) {
                int mi = 0; float mv = -1e30f;
                for (int i = 0; i < p; i++)
                    if (pos[i] > mv) { mv = pos[i]; mi = i; }
                thr = mv;
                pos[mi] = -1e30f;
            }
        }
        thr_s = thr;
    }
    __syncthreads();
    float thr = thr_s;
    for (int i = threadIdx.x; i < d; i += blockDim.x)
        keep[sj[i]] = (svc[i] >= thr) ? 1 : 0;
}

// ---------------- edge softmax by dst + aggregation + ELU (bf16 reads) -----
// block per dst node n. In-edges of n are rev(j) for j in src-CSR[n];
// in-edge rev(j): source=dst[j], e[rev(j)]==e[j] (symmetric), mask=keep[j].
__global__ __launch_bounds__(256) void aggregate(const int* __restrict__ offs,
                                                 const int* __restrict__ eid,
                                                 const int* __restrict__ dst,
                                                 const float* __restrict__ e,
                                                 const unsigned char* __restrict__ keep,
                                                 const unsigned short* __restrict__ fb,
                                                 unsigned short* __restrict__ zb) {
    int n = blockIdx.x;
    int s0 = offs[n];
    int d = offs[n + 1] - s0;
    if (d > MAXDEG) d = MAXDEG;
    __shared__ float sa[MAXDEG][NHEAD];  // 16 KB
    __shared__ int ssrc[MAXDEG];
    __shared__ float sm[NHEAD], ss[NHEAD];
    for (int i = threadIdx.x; i < d; i += blockDim.x) {
        int j = eid[s0 + i];
        ssrc[i] = dst[j];
        int kp = keep[j];
        const float* ep = e + (size_t)j * NHEAD;
        #pragma unroll
        for (int h = 0; h < NHEAD; h++) sa[i][h] = kp ? ep[h] : NEGV;
    }
    __syncthreads();
    if (threadIdx.x < NHEAD) {
        int h = threadIdx.x;
        float m = -INFINITY;
        for (int i = 0; i < d; i++) m = fmaxf(m, sa[i][h]);
        float s = 0.f;
        for (int i = 0; i < d; i++) s += expf(sa[i][h] - m);
        sm[h] = m; ss[h] = s;
    }
    __syncthreads();
    for (int i = threadIdx.x; i < d * NHEAD; i += blockDim.x) {
        int ii = i >> 3, h = i & 7;
        sa[ii][h] = expf(sa[ii][h] - sm[h]) / ss[h];
    }
    __syncthreads();
    int c0 = threadIdx.x * 2;
    int h = c0 >> 6;
    float acc0 = 0.f, acc1 = 0.f;
    for (int i = 0; i < d; i++) {
        const unsigned short* row = fb + (size_t)ssrc[i] * DIM;
        unsigned int v = *(const unsigned int*)(row + c0);
        float a = sa[i][h];
        acc0 += a * bf2f(v & 0xffffu);
        acc1 += a * bf2f(v >> 16);
    }
    acc0 = acc0 > 0.f ? acc0 : expf(acc0) - 1.f;   // elu
    acc1 = acc1 > 0.f ? acc1 : expf(acc1) - 1.f;
    zb[(size_t)n * DIM + c0] = f2bf(acc0);
    zb[(size_t)n * DIM + c0 + 1] = f2bf(acc1);
}

// ---------------- semantic attention scores (tiled GEMM + fused tanh) -------
// wsum[m] += sum over nodes of tanh(z_m @ w1 + b1) @ w2 ; z is bf16
#define SBM 64
#define SBN 128
#define SBK 32

__global__ __launch_bounds__(256) void sem_scores2(const unsigned short* __restrict__ z0,
                                                   const unsigned short* __restrict__ z1,
                                                   const float* __restrict__ w1,
                                                   const float* __restrict__ b1,
                                                   const float* __restrict__ w2,
                                                   float* wsum) {
    const unsigned short* Z = blockIdx.y ? z1 : z0;
    const int bm = blockIdx.x * SBM;
    const int tid = threadIdx.x;
    const int tx = tid & 15, ty = tid >> 4;
    __shared__ float Zs[SBK][SBM + 1];
    __shared__ float Ws[SBK][SBN + 1];
    float acc[4][8] = {};
    for (int kb = 0; kb < DIM; kb += SBK) {
        #pragma unroll
        for (int it = 0; it < 2; it++) {
            int r = (tid >> 3) + it * 32;
            int c = (tid & 7) * 4;
            const unsigned short* p = Z + (size_t)(bm + r) * DIM + kb + c;
            unsigned int v0 = *(const unsigned int*)(p);
            unsigned int v1 = *(const unsigned int*)(p + 2);
            Zs[c][r]     = bf2f(v0 & 0xffffu);
            Zs[c + 1][r] = bf2f(v0 >> 16);
            Zs[c + 2][r] = bf2f(v1 & 0xffffu);
            Zs[c + 3][r] = bf2f(v1 >> 16);
        }
        #pragma unroll
        for (int it = 0; it < 4; it++) {
            int k = (tid >> 5) + it * 8;
            int n = (tid & 31) * 4;
            float4 v = *(const float4*)(w1 + (size_t)(kb + k) * SBN + n);
            Ws[k][n] = v.x; Ws[k][n + 1] = v.y; Ws[k][n + 2] = v.z; Ws[k][n + 3] = v.w;
        }
        __syncthreads();
        #pragma unroll
        for (int k = 0; k < SBK; k++) {
            float a[4], b[8];
            #pragma unroll
            for (int i = 0; i < 4; i++) a[i] = Zs[k][ty * 4 + i];
            #pragma unroll
            for (int j = 0; j < 8; j++) b[j] = Ws[k][tx * 8 + j];
            #pragma unroll
            for (int i = 0; i < 4; i++)
                #pragma unroll
                for (int j = 0; j < 8; j++) acc[i][j] += a[i] * b[j];
        }
        __syncthreads();
    }
    float local = 0.f;
    #pragma unroll
    for (int j = 0; j < 8; j++) {
        int col = tx * 8 + j;
        float bb = b1[col], ww = w2[col];
        #pragma unroll
        for (int i = 0; i < 4; i++)
            local += tanhf(acc[i][j] + bb) * ww;
    }
    __shared__ float red[256];
    red[tid] = local;
    __syncthreads();
    for (int s = 128; s > 0; s >>= 1) {
        if (tid < s) red[tid] += red[tid + s];
        __syncthreads();
    }
    if (tid == 0) atomicAdd(&wsum[blockIdx.y], red[0]);
}

// ---------------- final: beta-weighted combine + linear ----------------
__global__ __launch_bounds__(256) void final_out(const unsigned short* __restrict__ z0,
                                                 const unsigned short* __restrict__ z1,
                                                 const float* __restrict__ wsum,
                                                 const float* __restrict__ lin_w,
                                                 const float* __restrict__ lin_b,
                                                 float* __restrict__ out) {
    int idx = blockIdx.x * 256 + threadIdx.x;   // 24576 threads
    int n = idx / 3, o = idx - n * 3;
    float w0 = wsum[0] * (1.0f / NN), w1v = wsum[1] * (1.0f / NN);
    float mx = fmaxf(w0, w1v);
    float e0 = expf(w0 - mx), e1 = expf(w1v - mx);
    float beta0 = e0 / (e0 + e1), beta1 = e1 / (e0 + e1);
    const unsigned short* p0 = z0 + (size_t)n * DIM;
    const unsigned short* p1 = z1 + (size_t)n * DIM;
    float acc = 0.f;
    for (int dd = 0; dd < DIM; dd++)
        acc += (beta0 * bf2f(p0[dd]) + beta1 * bf2f(p1[dd])) * lin_w[dd * 3 + o];
    out[idx] = acc + lin_b[o];
}

// ---------------- launch ----------------
extern "C" void kernel_launch(void* const* d_in, const int* in_sizes, int n_in,
                              void* d_out, int out_size, void* d_ws, size_t ws_size,
                              hipStream_t stream) {
    const float* feat = (const float*)d_in[0];
    const int*   srcp[2]   = { (const int*)d_in[1], (const int*)d_in[4] };
    const int*   dstp[2]   = { (const int*)d_in[2], (const int*)d_in[5] };
    const float* transp[2] = { (const float*)d_in[3], (const float*)d_in[6] };
    const float* fcw[2]    = { (const float*)d_in[7], (const float*)d_in[8] };
    const float* sem_w1 = (const float*)d_in[9];
    const float* sem_b1 = (const float*)d_in[10];
    const float* sem_w2 = (const float*)d_in[11];
    const float* lin_w  = (const float*)d_in[12];
    const float* lin_b  = (const float*)d_in[13];
    float* out = (float*)d_out;

    char* ws = (char*)d_ws;
    const size_t MB = 1 << 20;
    if (ws_size < 52 * MB) return;
    float*          f     = (float*)(ws);                       // 16 MB
    unsigned short* fb    = (unsigned short*)(ws + 16 * MB);    //  8 MB
    unsigned short* z0    = (unsigned short*)(ws + 24 * MB);    //  8 MB
    unsigned short* z1    = (unsigned short*)(ws + 32 * MB);    //  8 MB
    float*          e     = (float*)(ws + 40 * MB);             //  8 MB
    float*          vals  = (float*)(ws + 48 * MB);             //  1 MB
    int*            eid   = (int*)  (ws + 49 * MB);             //  1 MB
    unsigned char*  keep  = (unsigned char*)(ws + 50 * MB);     // 256 KB
    int*            counts= (int*)  (ws + 50 * MB + 262144);    // 32 KB
    int*            offs  = (int*)  (ws + 50 * MB + 262144 + 32768);
    int*            cur   = (int*)  (ws + 50 * MB + 262144 + 2 * 32768 + 4096);
    float*          wsum  = (float*)(ws + 50 * MB + 262144 + 3 * 32768 + 8192);

    for (int c = 0; c < 2; c++) {
        unsigned short* z = c ? z1 : z0;
        hipMemsetAsync(counts, 0, NN * sizeof(int), stream);
        count_src<<<NE / 256, 256, 0, stream>>>(srcp[c], counts);
        scan_offs<<<1, 256, 0, stream>>>(counts, offs, cur);
        scatter_src<<<NE / 256, 256, 0, stream>>>(srcp[c], cur, eid);
        gemm_f<<<dim3(DIM / BN, NN / BM), 256, 0, stream>>>(feat, fcw[c], f, fb);
        edge_dots_csr<<<NN, 256, 0, stream>>>(f, offs, eid, dstp[c], transp[c], e, vals);
        row_thresh<<<NN, 128, 0, stream>>>(offs, eid, dstp[c], vals, keep);
        aggregate<<<NN, 256, 0, stream>>>(offs, eid, dstp[c], e, keep, fb, z);
    }
    hipMemsetAsync(wsum, 0, 2 * sizeof(float), stream);
    sem_scores2<<<dim3(NN / SBM, 2), 256, 0, stream>>>(z0, z1, sem_w1, sem_b1, sem_w2, wsum);
    final_out<<<(NN * 3) / 256, 256, 0, stream>>>(z0, z1, wsum, lin_w, lin_b, out);
}

// Round 4
// 684.254 us; speedup vs baseline: 1.5048x; 1.1026x over previous
//
#include <hip/hip_runtime.h>
#include <math.h>

#define NN      8192
#define DIM     512      // IN_DIM == H*HID
#define NHEAD   8
#define HID     64
#define NE      262144
#define NE_HALF 131072
#define TOPK    10
#define NEGV    -9e15f
#define MAXDEG  512

typedef __attribute__((ext_vector_type(8))) short short8;
typedef __attribute__((ext_vector_type(4))) float f32x4;

__device__ __forceinline__ float bf2f(unsigned int h) {
    return __uint_as_float(h << 16);
}
__device__ __forceinline__ unsigned short f2bf(float x) {
    unsigned int u = __float_as_uint(x);
    unsigned int r = (u + 0x7fff + ((u >> 16) & 1)) >> 16;   // RNE
    return (unsigned short)r;
}

// ---------------- split fp32 -> (hi, lo) bf16 ----------------
__global__ __launch_bounds__(256) void split_feat(const float* __restrict__ X,
                                                  unsigned short* __restrict__ H,
                                                  unsigned short* __restrict__ L) {
    int i = blockIdx.x * 256 + threadIdx.x;           // over float4s
    float4 v = ((const float4*)X)[i];
    unsigned short h0 = f2bf(v.x), h1 = f2bf(v.y), h2 = f2bf(v.z), h3 = f2bf(v.w);
    ushort4 hv; hv.x = h0; hv.y = h1; hv.z = h2; hv.w = h3;
    ushort4 lv;
    lv.x = f2bf(v.x - bf2f(h0));
    lv.y = f2bf(v.y - bf2f(h1));
    lv.z = f2bf(v.z - bf2f(h2));
    lv.w = f2bf(v.w - bf2f(h3));
    ((ushort4*)H)[i] = hv;
    ((ushort4*)L)[i] = lv;
}

// W[512][512] fp32 -> transposed split Th/Tl [n][k] bf16
__global__ __launch_bounds__(256) void split_w(const float* __restrict__ W,
                                               unsigned short* __restrict__ Th,
                                               unsigned short* __restrict__ Tl) {
    __shared__ float t[32][33];
    int k0 = blockIdx.y * 32, n0 = blockIdx.x * 32;
    int tx = threadIdx.x & 31, ty = threadIdx.x >> 5;   // ty 0..7
    #pragma unroll
    for (int i = 0; i < 4; i++)
        t[ty + 8 * i][tx] = W[(size_t)(k0 + ty + 8 * i) * DIM + n0 + tx];
    __syncthreads();
    #pragma unroll
    for (int i = 0; i < 4; i++) {
        float x = t[tx][ty + 8 * i];
        unsigned short h = f2bf(x);
        size_t off = (size_t)(n0 + ty + 8 * i) * DIM + k0 + tx;
        Th[off] = h;
        Tl[off] = f2bf(x - bf2f(h));
    }
}

// ---------------- MFMA GEMM: C = (Ah+Al) @ (Bh+Bl)^T, 3-pass split-bf16 ----
// A* : [8192][512] bf16 row-major; B* : [512][512] bf16 [n][k] (transposed)
// Output split: Ch + Cl (bf16 hi/lo), C ~ fp32 to ~1e-5 rel.
__global__ __launch_bounds__(256) void gemm_mfma(const unsigned short* __restrict__ Ah,
                                                 const unsigned short* __restrict__ Al,
                                                 const unsigned short* __restrict__ Bh,
                                                 const unsigned short* __restrict__ Bl,
                                                 unsigned short* __restrict__ Ch,
                                                 unsigned short* __restrict__ Cl) {
    __shared__ unsigned short As[128][32];   // 8 KB
    __shared__ unsigned short Bs[128][32];   // 8 KB
    const int bm = blockIdx.y * 128;
    const int bn = blockIdx.x * 128;
    const int tid = threadIdx.x;
    const int lane = tid & 63;
    const int wave = tid >> 6;
    const int wm = (wave >> 1) * 64, wn = (wave & 1) * 64;
    const int fr = lane & 15, fq = lane >> 4;
    const int sr = tid >> 2, sc = (tid & 3) * 8;   // staging: row sr(/+64), k-offset sc
    f32x4 acc[4][4] = {};
    const unsigned short* Ap[3] = { Ah, Al, Ah };
    const unsigned short* Bp[3] = { Bh, Bh, Bl };
    for (int p = 0; p < 3; p++) {
        const unsigned short* Ag = Ap[p] + (size_t)(bm + sr) * DIM + sc;
        const unsigned short* Bg = Bp[p] + (size_t)(bn + sr) * DIM + sc;
        for (int kb = 0; kb < DIM; kb += 32) {
            __syncthreads();   // prior reads of LDS done
            __builtin_amdgcn_global_load_lds(
                (const __attribute__((address_space(1))) void*)(Ag + kb),
                (__attribute__((address_space(3))) void*)(&As[sr][sc]), 16, 0, 0);
            __builtin_amdgcn_global_load_lds(
                (const __attribute__((address_space(1))) void*)(Ag + (size_t)64 * DIM + kb),
                (__attribute__((address_space(3))) void*)(&As[sr + 64][sc]), 16, 0, 0);
            __builtin_amdgcn_global_load_lds(
                (const __attribute__((address_space(1))) void*)(Bg + kb),
                (__attribute__((address_space(3))) void*)(&Bs[sr][sc]), 16, 0, 0);
            __builtin_amdgcn_global_load_lds(
                (const __attribute__((address_space(1))) void*)(Bg + (size_t)64 * DIM + kb),
                (__attribute__((address_space(3))) void*)(&Bs[sr + 64][sc]), 16, 0, 0);
            __syncthreads();   // vmcnt(0) drained by barrier semantics
            short8 af[4], bfv[4];
            #pragma unroll
            for (int i = 0; i < 4; i++)
                af[i] = *(const short8*)&As[wm + i * 16 + fr][fq * 8];
            #pragma unroll
            for (int i = 0; i < 4; i++)
                bfv[i] = *(const short8*)&Bs[wn + i * 16 + fr][fq * 8];
            #pragma unroll
            for (int mi = 0; mi < 4; mi++)
                #pragma unroll
                for (int ni = 0; ni < 4; ni++)
                    acc[mi][ni] = __builtin_amdgcn_mfma_f32_16x16x32_bf16(
                        af[mi], bfv[ni], acc[mi][ni], 0, 0, 0);
        }
    }
    #pragma unroll
    for (int mi = 0; mi < 4; mi++)
        #pragma unroll
        for (int ni = 0; ni < 4; ni++)
            #pragma unroll
            for (int r = 0; r < 4; r++) {
                int row = bm + wm + mi * 16 + fq * 4 + r;
                int col = bn + wn + ni * 16 + fr;
                float v = acc[mi][ni][r];
                unsigned short h = f2bf(v);
                size_t off = (size_t)row * DIM + col;
                Ch[off] = h;
                Cl[off] = f2bf(v - bf2f(h));
            }
}

// ---------------- CSR by src ----------------
__global__ __launch_bounds__(256) void count_src(const int* __restrict__ src, int* counts) {
    int j = blockIdx.x * 256 + threadIdx.x;
    atomicAdd(&counts[src[j]], 1);
}

__global__ __launch_bounds__(256) void scan_offs(const int* __restrict__ counts,
                                                 int* __restrict__ offs, int* __restrict__ cur) {
    __shared__ int part[256];
    int t = threadIdx.x;
    int base = t * 32;
    int s = 0;
    for (int i = 0; i < 32; i++) s += counts[base + i];
    part[t] = s;
    __syncthreads();
    if (t == 0) {
        int run = 0;
        for (int i = 0; i < 256; i++) { int v = part[i]; part[i] = run; run += v; }
        offs[NN] = run;
    }
    __syncthreads();
    int run = part[t];
    for (int i = 0; i < 32; i++) {
        offs[base + i] = run;
        cur[base + i] = run;
        run += counts[base + i];
    }
}

__global__ __launch_bounds__(256) void scatter_src(const int* __restrict__ src,
                                                   int* cur, int* __restrict__ eid) {
    int j = blockIdx.x * 256 + threadIdx.x;
    int p = atomicAdd(&cur[src[j]], 1);
    eid[p] = j;
}

// ---------------- per-edge per-head dots + vals (CSR order, split-bf16 f) ---
// e[j][h] = head-h dot of f[src[j]],f[dst[j]]  (symmetric: e[rev(j)]==e[j])
__global__ __launch_bounds__(256) void edge_dots_csr(const unsigned short* __restrict__ Ch,
                                                     const unsigned short* __restrict__ Cl,
                                                     const int* __restrict__ offs,
                                                     const int* __restrict__ eid,
                                                     const int* __restrict__ dst,
                                                     const float* __restrict__ trans,
                                                     float* __restrict__ e,
                                                     float* __restrict__ vals) {
    int n = blockIdx.x;
    int s0 = offs[n];
    int d = offs[n + 1] - s0;
    if (d <= 0) return;
    int wave = threadIdx.x >> 6, lane = threadIdx.x & 63;
    const uint4* ph = (const uint4*)(Ch + (size_t)n * DIM);
    const uint4* pl = (const uint4*)(Cl + (size_t)n * DIM);
    uint4 hv = ph[lane], lv = pl[lane];
    float a[8];
    a[0] = bf2f(hv.x & 0xffffu) + bf2f(lv.x & 0xffffu);
    a[1] = bf2f(hv.x >> 16)     + bf2f(lv.x >> 16);
    a[2] = bf2f(hv.y & 0xffffu) + bf2f(lv.y & 0xffffu);
    a[3] = bf2f(hv.y >> 16)     + bf2f(lv.y >> 16);
    a[4] = bf2f(hv.z & 0xffffu) + bf2f(lv.z & 0xffffu);
    a[5] = bf2f(hv.z >> 16)     + bf2f(lv.z >> 16);
    a[6] = bf2f(hv.w & 0xffffu) + bf2f(lv.w & 0xffffu);
    a[7] = bf2f(hv.w >> 16)     + bf2f(lv.w >> 16);
    for (int i = wave; i < d; i += 4) {
        int j = eid[s0 + i];
        const uint4* qh = (const uint4*)(Ch + (size_t)dst[j] * DIM);
        const uint4* ql = (const uint4*)(Cl + (size_t)dst[j] * DIM);
        uint4 bh = qh[lane], bl = ql[lane];
        float p;
        p  = a[0] * (bf2f(bh.x & 0xffffu) + bf2f(bl.x & 0xffffu));
        p += a[1] * (bf2f(bh.x >> 16)     + bf2f(bl.x >> 16));
        p += a[2] * (bf2f(bh.y & 0xffffu) + bf2f(bl.y & 0xffffu));
        p += a[3] * (bf2f(bh.y >> 16)     + bf2f(bl.y >> 16));
        p += a[4] * (bf2f(bh.z & 0xffffu) + bf2f(bl.z & 0xffffu));
        p += a[5] * (bf2f(bh.z >> 16)     + bf2f(bl.z >> 16));
        p += a[6] * (bf2f(bh.w & 0xffffu) + bf2f(bl.w & 0xffffu));
        p += a[7] * (bf2f(bh.w >> 16)     + bf2f(bl.w >> 16));
        p += __shfl_xor(p, 1);
        p += __shfl_xor(p, 2);
        p += __shfl_xor(p, 4);           // per-head sums (head = lane>>3)
        if ((lane & 7) == 0) e[(size_t)j * NHEAD + (lane >> 3)] = p;
        p += __shfl_xor(p, 8);
        p += __shfl_xor(p, 16);
        p += __shfl_xor(p, 32);          // full 512-dim sum
        if (lane == 0) vals[j] = trans[j] * p;
    }
}

// ---------------- per-row coalesce + top-T threshold -> keep flags ----------
__global__ __launch_bounds__(128) void row_thresh(const int* __restrict__ offs,
                                                  const int* __restrict__ eid,
                                                  const int* __restrict__ dst,
                                                  const float* __restrict__ vals,
                                                  unsigned char* __restrict__ keep) {
    int r = blockIdx.x;
    int s0 = offs[r];
    int d = offs[r + 1] - s0;
    if (d > MAXDEG) d = MAXDEG;
    __shared__ int   sc[MAXDEG];
    __shared__ float sv[MAXDEG];
    __shared__ int   sj[MAXDEG];
    __shared__ float svc[MAXDEG];
    __shared__ unsigned char lead[MAXDEG];
    __shared__ float pos[MAXDEG];
    __shared__ float thr_s;
    for (int i = threadIdx.x; i < d; i += blockDim.x) {
        int j = eid[s0 + i];
        sj[i] = j; sc[i] = dst[j]; sv[i] = vals[j];
    }
    __syncthreads();
    for (int i = threadIdx.x; i < d; i += blockDim.x) {
        int c = sc[i];
        float sum = 0.f;
        bool leader = true;
        for (int k = 0; k < d; k++) {
            if (sc[k] == c) {
                sum += sv[k];
                if (k < i) leader = false;
            }
        }
        svc[i] = sum;
        lead[i] = leader ? 1 : 0;
    }
    __syncthreads();
    if (threadIdx.x == 0) {
        int p = 0;
        for (int i = 0; i < d; i++)
            if (lead[i] && svc[i] > 0.f) pos[p++] = svc[i];
        float thr = 0.f;
        if (p >= TOPK) {
            for (int t = 0; t < TOPK; t++) {
                int mi = 0; float mv = -1e30f;
                for (int i = 0; i < p; i++)
                    if (pos[i] > mv) { mv = pos[i]; mi = i; }
                thr = mv;
                pos[mi] = -1e30f;
            }
        }
        thr_s = thr;
    }
    __syncthreads();
    float thr = thr_s;
    for (int i = threadIdx.x; i < d; i += blockDim.x)
        keep[sj[i]] = (svc[i] >= thr) ? 1 : 0;
}

// ---------------- edge softmax by dst + aggregation + ELU (bf16 reads) -----
__global__ __launch_bounds__(256) void aggregate(const int* __restrict__ offs,
                                                 const int* __restrict__ eid,
                                                 const int* __restrict__ dst,
                                                 const float* __restrict__ e,
                                                 const unsigned char* __restrict__ keep,
                                                 const unsigned short* __restrict__ fb,
                                                 unsigned short* __restrict__ zb) {
    int n = blockIdx.x;
    int s0 = offs[n];
    int d = offs[n + 1] - s0;
    if (d > MAXDEG) d = MAXDEG;
    __shared__ float sa[MAXDEG][NHEAD];  // 16 KB
    __shared__ int ssrc[MAXDEG];
    __shared__ float sm[NHEAD], ss[NHEAD];
    for (int i = threadIdx.x; i < d; i += blockDim.x) {
        int j = eid[s0 + i];
        ssrc[i] = dst[j];
        int kp = keep[j];
        const float* ep = e + (size_t)j * NHEAD;
        #pragma unroll
        for (int h = 0; h < NHEAD; h++) sa[i][h] = kp ? ep[h] : NEGV;
    }
    __syncthreads();
    if (threadIdx.x < NHEAD) {
        int h = threadIdx.x;
        float m = -INFINITY;
        for (int i = 0; i < d; i++) m = fmaxf(m, sa[i][h]);
        float s = 0.f;
        for (int i = 0; i < d; i++) s += expf(sa[i][h] - m);
        sm[h] = m; ss[h] = s;
    }
    __syncthreads();
    for (int i = threadIdx.x; i < d * NHEAD; i += blockDim.x) {
        int ii = i >> 3, h = i & 7;
        sa[ii][h] = expf(sa[ii][h] - sm[h]) / ss[h];
    }
    __syncthreads();
    int c0 = threadIdx.x * 2;
    int h = c0 >> 6;
    float acc0 = 0.f, acc1 = 0.f;
    for (int i = 0; i < d; i++) {
        const unsigned short* row = fb + (size_t)ssrc[i] * DIM;
        unsigned int v = *(const unsigned int*)(row + c0);
        float a = sa[i][h];
        acc0 += a * bf2f(v & 0xffffu);
        acc1 += a * bf2f(v >> 16);
    }
    acc0 = acc0 > 0.f ? acc0 : expf(acc0) - 1.f;   // elu
    acc1 = acc1 > 0.f ? acc1 : expf(acc1) - 1.f;
    zb[(size_t)n * DIM + c0] = f2bf(acc0);
    zb[(size_t)n * DIM + c0 + 1] = f2bf(acc1);
}

// ---------------- semantic attention scores (tiled GEMM + fused tanh) -------
#define SBM 64
#define SBN 128
#define SBK 32

__global__ __launch_bounds__(256) void sem_scores2(const unsigned short* __restrict__ z0,
                                                   const unsigned short* __restrict__ z1,
                                                   const float* __restrict__ w1,
                                                   const float* __restrict__ b1,
                                                   const float* __restrict__ w2,
                                                   float* wsum) {
    const unsigned short* Z = blockIdx.y ? z1 : z0;
    const int bm = blockIdx.x * SBM;
    const int tid = threadIdx.x;
    const int tx = tid & 15, ty = tid >> 4;
    __shared__ float Zs[SBK][SBM + 1];
    __shared__ float Ws[SBK][SBN + 1];
    float acc[4][8] = {};
    for (int kb = 0; kb < DIM; kb += SBK) {
        #pragma unroll
        for (int it = 0; it < 2; it++) {
            int r = (tid >> 3) + it * 32;
            int c = (tid & 7) * 4;
            const unsigned short* p = Z + (size_t)(bm + r) * DIM + kb + c;
            unsigned int v0 = *(const unsigned int*)(p);
            unsigned int v1 = *(const unsigned int*)(p + 2);
            Zs[c][r]     = bf2f(v0 & 0xffffu);
            Zs[c + 1][r] = bf2f(v0 >> 16);
            Zs[c + 2][r] = bf2f(v1 & 0xffffu);
            Zs[c + 3][r] = bf2f(v1 >> 16);
        }
        #pragma unroll
        for (int it = 0; it < 4; it++) {
            int k = (tid >> 5) + it * 8;
            int n = (tid & 31) * 4;
            float4 v = *(const float4*)(w1 + (size_t)(kb + k) * SBN + n);
            Ws[k][n] = v.x; Ws[k][n + 1] = v.y; Ws[k][n + 2] = v.z; Ws[k][n + 3] = v.w;
        }
        __syncthreads();
        #pragma unroll
        for (int k = 0; k < SBK; k++) {
            float a[4], b[8];
            #pragma unroll
            for (int i = 0; i < 4; i++) a[i] = Zs[k][ty * 4 + i];
            #pragma unroll
            for (int j = 0; j < 8; j++) b[j] = Ws[k][tx * 8 + j];
            #pragma unroll
            for (int i = 0; i < 4; i++)
                #pragma unroll
                for (int j = 0; j < 8; j++) acc[i][j] += a[i] * b[j];
        }
        __syncthreads();
    }
    float local = 0.f;
    #pragma unroll
    for (int j = 0; j < 8; j++) {
        int col = tx * 8 + j;
        float bb = b1[col], ww = w2[col];
        #pragma unroll
        for (int i = 0; i < 4; i++)
            local += tanhf(acc[i][j] + bb) * ww;
    }
    __shared__ float red[256];
    red[tid] = local;
    __syncthreads();
    for (int s = 128; s > 0; s >>= 1) {
        if (tid < s) red[tid] += red[tid + s];
        __syncthreads();
    }
    if (tid == 0) atomicAdd(&wsum[blockIdx.y], red[0]);
}

// ---------------- final: beta-weighted combine + linear ----------------
__global__ __launch_bounds__(256) void final_out(const unsigned short* __restrict__ z0,
                                                 const unsigned short* __restrict__ z1,
                                                 const float* __restrict__ wsum,
                                                 const float* __restrict__ lin_w,
                                                 const float* __restrict__ lin_b,
                                                 float* __restrict__ out) {
    int idx = blockIdx.x * 256 + threadIdx.x;   // 24576 threads
    int n = idx / 3, o = idx - n * 3;
    float w0 = wsum[0] * (1.0f / NN), w1v = wsum[1] * (1.0f / NN);
    float mx = fmaxf(w0, w1v);
    float e0 = expf(w0 - mx), e1 = expf(w1v - mx);
    float beta0 = e0 / (e0 + e1), beta1 = e1 / (e0 + e1);
    const unsigned short* p0 = z0 + (size_t)n * DIM;
    const unsigned short* p1 = z1 + (size_t)n * DIM;
    float acc = 0.f;
    for (int dd = 0; dd < DIM; dd++)
        acc += (beta0 * bf2f(p0[dd]) + beta1 * bf2f(p1[dd])) * lin_w[dd * 3 + o];
    out[idx] = acc + lin_b[o];
}

// ---------------- launch ----------------
extern "C" void kernel_launch(void* const* d_in, const int* in_sizes, int n_in,
                              void* d_out, int out_size, void* d_ws, size_t ws_size,
                              hipStream_t stream) {
    const float* feat = (const float*)d_in[0];
    const int*   srcp[2]   = { (const int*)d_in[1], (const int*)d_in[4] };
    const int*   dstp[2]   = { (const int*)d_in[2], (const int*)d_in[5] };
    const float* transp[2] = { (const float*)d_in[3], (const float*)d_in[6] };
    const float* fcw[2]    = { (const float*)d_in[7], (const float*)d_in[8] };
    const float* sem_w1 = (const float*)d_in[9];
    const float* sem_b1 = (const float*)d_in[10];
    const float* sem_w2 = (const float*)d_in[11];
    const float* lin_w  = (const float*)d_in[12];
    const float* lin_b  = (const float*)d_in[13];
    float* out = (float*)d_out;

    char* ws = (char*)d_ws;
    const size_t MB = 1 << 20;
    if (ws_size < 60 * MB) return;
    unsigned short* Ch    = (unsigned short*)(ws);               //  8 MB
    unsigned short* Cl    = (unsigned short*)(ws + 8 * MB);      //  8 MB
    unsigned short* z0    = (unsigned short*)(ws + 16 * MB);     //  8 MB
    unsigned short* z1    = (unsigned short*)(ws + 24 * MB);     //  8 MB
    float*          e     = (float*)(ws + 32 * MB);              //  8 MB
    unsigned short* fH    = (unsigned short*)(ws + 40 * MB);     //  8 MB
    unsigned short* fL    = (unsigned short*)(ws + 48 * MB);     //  8 MB
    float*          vals  = (float*)(ws + 56 * MB);              //  1 MB
    int*            eid   = (int*)  (ws + 57 * MB);              //  1 MB
    unsigned short* BhT   = (unsigned short*)(ws + 58 * MB);     // 512 KB
    unsigned short* BlT   = (unsigned short*)(ws + 58 * MB + 524288);
    unsigned char*  keep  = (unsigned char*)(ws + 59 * MB);      // 256 KB
    int*            counts= (int*)  (ws + 59 * MB + 262144);     // 32 KB
    int*            offs  = (int*)  (ws + 59 * MB + 262144 + 32768);
    int*            cur   = (int*)  (ws + 59 * MB + 262144 + 32768 + 36864);
    float*          wsum  = (float*)(ws + 59 * MB + 262144 + 32768 + 36864 + 32768);

    split_feat<<<(NN * DIM / 4) / 256, 256, 0, stream>>>(feat, fH, fL);
    for (int c = 0; c < 2; c++) {
        unsigned short* z = c ? z1 : z0;
        hipMemsetAsync(counts, 0, NN * sizeof(int), stream);
        count_src<<<NE / 256, 256, 0, stream>>>(srcp[c], counts);
        scan_offs<<<1, 256, 0, stream>>>(counts, offs, cur);
        scatter_src<<<NE / 256, 256, 0, stream>>>(srcp[c], cur, eid);
        split_w<<<dim3(16, 16), 256, 0, stream>>>(fcw[c], BhT, BlT);
        gemm_mfma<<<dim3(4, 64), 256, 0, stream>>>(fH, fL, BhT, BlT, Ch, Cl);
        edge_dots_csr<<<NN, 256, 0, stream>>>(Ch, Cl, offs, eid, dstp[c], transp[c], e, vals);
        row_thresh<<<NN, 128, 0, stream>>>(offs, eid, dstp[c], vals, keep);
        aggregate<<<NN, 256, 0, stream>>>(offs, eid, dstp[c], e, keep, Ch, z);
    }
    hipMemsetAsync(wsum, 0, 2 * sizeof(float), stream);
    sem_scores2<<<dim3(NN / SBM, 2), 256, 0, stream>>>(z0, z1, sem_w1, sem_b1, sem_w2, wsum);
    final_out<<<(NN * 3) / 256, 256, 0, stream>>>(z0, z1, wsum, lin_w, lin_b, out);
}